// Round 1
// baseline (3425.462 us; speedup 1.0000x reference)
//
#include <hip/hip_runtime.h>

#define TOKENS 2048
#define DM 1024
#define NHEAD 16
#define DH 64
#define SEQL 512
#define NBATCH 4
#define DFFN 4096
#define NLAYER 6
#define NVOCAB 32000

typedef short short8 __attribute__((ext_vector_type(8)));
typedef short short4v __attribute__((ext_vector_type(4)));
typedef float floatx4 __attribute__((ext_vector_type(4)));

#define FLAG_RELU 1
#define FLAG_OUTBF16 2
#define FLAG_CSKIP 4
#define FLAG_CKLIM 8

__device__ __forceinline__ float bf2f(short s) {
  unsigned u = ((unsigned)(unsigned short)s) << 16;
  return __builtin_bit_cast(float, u);
}
__device__ __forceinline__ short f2bf(float f) {
  unsigned u = __builtin_bit_cast(unsigned, f);
  u = (u + 0x7FFFu + ((u >> 16) & 1u)) >> 16;
  return (short)(unsigned short)u;
}

// ---------------------------------------------------------------------------
// Generic GEMM: C[M,N] = alpha * A[M,K] (bf16) x Bt[N,K]^T  (+bias +resid, relu)
// Bt is K-contiguous ("B transposed"); BT_F32 converts fp32 Bt on the fly.
// 128x128 tile, BK=32, 256 threads = 4 waves, each wave 64x64 via 4x4 MFMAs.
// LDS row stride 40 bf16 (80B): 16B-aligned ds_read_b128, <=2-way bank alias.
// ---------------------------------------------------------------------------
template<bool BT_F32>
__global__ __launch_bounds__(256) void gemm_bt(
    const short* __restrict__ A, const void* __restrict__ Bt, void* __restrict__ Cv,
    const float* __restrict__ bias, const float* __restrict__ resid,
    int M, int N, int K, int lda, int ldb, int ldc,
    long A_sb, long A_sh, long B_sb, long B_sh, long C_sb, long C_sh,
    int Hdiv, float alpha, int flags)
{
  const int row0 = blockIdx.y * 128, col0 = blockIdx.x * 128;
  if ((flags & FLAG_CSKIP) && col0 > row0 + 127) return;
  const int z = blockIdx.z;
  const int bz = z / Hdiv, hz = z % Hdiv;
  const short* Ab = A + bz * A_sb + hz * A_sh;
  const long boff = bz * B_sb + hz * B_sh;
  const long coff = bz * C_sb + hz * C_sh;

  __shared__ short As[128 * 40];
  __shared__ short Bs[128 * 40];

  const int tid = threadIdx.x;
  const int lane = tid & 63;
  const int wid = tid >> 6;
  const int wr = wid >> 1, wc = wid & 1;
  const int lc = lane & 15, g = lane >> 4;

  floatx4 acc[4][4];
  #pragma unroll
  for (int i = 0; i < 4; ++i)
    #pragma unroll
    for (int j = 0; j < 4; ++j)
      acc[i][j] = (floatx4){0.f, 0.f, 0.f, 0.f};

  int kmax = K;
  if (flags & FLAG_CKLIM) kmax = min(K, row0 + 128);

  for (int k0 = 0; k0 < kmax; k0 += 32) {
    #pragma unroll
    for (int it = 0; it < 2; ++it) {
      int chunk = tid + it * 256;
      int r = chunk >> 2, cc = chunk & 3;
      // A tile: rows always in-bounds (M multiple of 128 in all uses)
      *(short8*)&As[r * 40 + cc * 8] =
          *(const short8*)(Ab + (long)(row0 + r) * lda + k0 + cc * 8);
      // B tile (guard N)
      short8 vb = {0, 0, 0, 0, 0, 0, 0, 0};
      int nr = col0 + r;
      if (nr < N) {
        if constexpr (BT_F32) {
          const float* bp = (const float*)Bt + boff + (long)nr * ldb + k0 + cc * 8;
          float4 u0 = *(const float4*)(bp);
          float4 u1 = *(const float4*)(bp + 4);
          vb[0] = f2bf(u0.x); vb[1] = f2bf(u0.y); vb[2] = f2bf(u0.z); vb[3] = f2bf(u0.w);
          vb[4] = f2bf(u1.x); vb[5] = f2bf(u1.y); vb[6] = f2bf(u1.z); vb[7] = f2bf(u1.w);
        } else {
          vb = *(const short8*)((const short*)Bt + boff + (long)nr * ldb + k0 + cc * 8);
        }
      }
      *(short8*)&Bs[r * 40 + cc * 8] = vb;
    }
    __syncthreads();

    short8 fa[4], fb[4];
    #pragma unroll
    for (int i = 0; i < 4; ++i)
      fa[i] = *(const short8*)&As[(wr * 64 + i * 16 + lc) * 40 + g * 8];
    #pragma unroll
    for (int j = 0; j < 4; ++j)
      fb[j] = *(const short8*)&Bs[(wc * 64 + j * 16 + lc) * 40 + g * 8];
    #pragma unroll
    for (int i = 0; i < 4; ++i)
      #pragma unroll
      for (int j = 0; j < 4; ++j)
        acc[i][j] = __builtin_amdgcn_mfma_f32_16x16x32_bf16(fa[i], fb[j], acc[i][j], 0, 0, 0);
    __syncthreads();
  }

  const bool relu = flags & FLAG_RELU;
  const bool obf  = flags & FLAG_OUTBF16;
  float* Cf = (float*)Cv;
  short* Cb = (short*)Cv;
  #pragma unroll
  for (int i = 0; i < 4; ++i) {
    int orow = row0 + wr * 64 + i * 16 + g * 4;   // C/D: row = 4*(lane>>4)+t
    #pragma unroll
    for (int j = 0; j < 4; ++j) {
      int ocol = col0 + wc * 64 + j * 16 + lc;    // C/D: col = lane&15
      if (ocol >= N) continue;
      #pragma unroll
      for (int t = 0; t < 4; ++t) {
        long off = coff + (long)(orow + t) * ldc + ocol;
        float v = alpha * acc[i][j][t];
        if (bias)  v += bias[ocol];
        if (resid) v += resid[off];
        if (relu)  v = fmaxf(v, 0.f);
        if (obf) Cb[off] = f2bf(v); else Cf[off] = v;
      }
    }
  }
}

// ---------------------------------------------------------------------------
// LayerNorm (population std, /(std+eps)) fp32 in -> bf16 out. 1 block per row.
// ---------------------------------------------------------------------------
__global__ __launch_bounds__(256) void ln_bf16(const float* __restrict__ x,
    const float* __restrict__ gg, const float* __restrict__ bb, short* __restrict__ out)
{
  int row = blockIdx.x;
  const float4 u = ((const float4*)(x + (long)row * DM))[threadIdx.x];
  float s  = u.x + u.y + u.z + u.w;
  float sq = u.x * u.x + u.y * u.y + u.z * u.z + u.w * u.w;
  #pragma unroll
  for (int o = 32; o; o >>= 1) { s += __shfl_xor(s, o); sq += __shfl_xor(sq, o); }
  __shared__ float red[8];
  int lane = threadIdx.x & 63, wid = threadIdx.x >> 6;
  if (lane == 0) { red[wid] = s; red[4 + wid] = sq; }
  __syncthreads();
  s  = red[0] + red[1] + red[2] + red[3];
  sq = red[4] + red[5] + red[6] + red[7];
  float mu  = s * (1.f / DM);
  float var = fmaxf(sq * (1.f / DM) - mu * mu, 0.f);
  float inv = 1.f / (sqrtf(var) + 1e-6f);
  int c = threadIdx.x * 4;
  const float4 gv = ((const float4*)gg)[threadIdx.x];
  const float4 bv = ((const float4*)bb)[threadIdx.x];
  short4v o;
  o[0] = f2bf((u.x - mu) * inv * gv.x + bv.x);
  o[1] = f2bf((u.y - mu) * inv * gv.y + bv.y);
  o[2] = f2bf((u.z - mu) * inv * gv.z + bv.z);
  o[3] = f2bf((u.w - mu) * inv * gv.w + bv.w);
  *(short4v*)(out + (long)row * DM + c) = o;
}

// ---------------------------------------------------------------------------
// Embedding: x = tok_emb[tok]*sqrt(D) + pos_emb[s]
// ---------------------------------------------------------------------------
__global__ __launch_bounds__(256) void embed_k(const int* __restrict__ toks,
    const float* __restrict__ emb, const float* __restrict__ pos, float* __restrict__ x)
{
  int row = blockIdx.x;
  int s = row & (SEQL - 1);
  long tk = toks[row];
  const float4 e = ((const float4*)(emb + tk * DM))[threadIdx.x];
  const float4 p = ((const float4*)(pos + (long)s * DM))[threadIdx.x];
  float4 o;
  o.x = e.x * 32.f + p.x; o.y = e.y * 32.f + p.y;
  o.z = e.z * 32.f + p.z; o.w = e.w * 32.f + p.w;
  ((float4*)(x + (long)row * DM))[threadIdx.x] = o;
}

// ---------------------------------------------------------------------------
// Causal softmax in-place on bf16 scores [B*H*S, S]; one wave per row.
// ---------------------------------------------------------------------------
__global__ __launch_bounds__(256) void softmax_causal(short* __restrict__ Sc)
{
  int wid = threadIdx.x >> 6, lane = threadIdx.x & 63;
  long row = (long)blockIdx.x * 4 + wid;
  int q = (int)(row & (SEQL - 1));
  short8* rp = (short8*)(Sc + row * SEQL);
  short8 v = rp[lane];
  int base = lane * 8;
  float f[8], mx = -3e38f;
  #pragma unroll
  for (int e = 0; e < 8; ++e) {
    f[e] = (base + e <= q) ? bf2f(v[e]) : -3e38f;
    mx = fmaxf(mx, f[e]);
  }
  #pragma unroll
  for (int o = 32; o; o >>= 1) mx = fmaxf(mx, __shfl_xor(mx, o));
  float sum = 0.f;
  #pragma unroll
  for (int e = 0; e < 8; ++e) {
    float p = (base + e <= q) ? __expf(f[e] - mx) : 0.f;
    f[e] = p; sum += p;
  }
  #pragma unroll
  for (int o = 32; o; o >>= 1) sum += __shfl_xor(sum, o);
  float inv = 1.f / sum;
  short8 o8;
  #pragma unroll
  for (int e = 0; e < 8; ++e) o8[e] = f2bf(f[e] * inv);
  rp[lane] = o8;
}

// ---------------------------------------------------------------------------
// Weight transpose+convert: W fp32 [z][K][N] -> Wt bf16 [z][N][K]
// ---------------------------------------------------------------------------
__global__ void wtrans(const float* __restrict__ W, short* __restrict__ Wt, int K, int N)
{
  __shared__ float tile[32][33];
  const long lo = (long)blockIdx.z * K * N;
  int n0 = blockIdx.x * 32, k0 = blockIdx.y * 32;
  int tx = threadIdx.x, ty = threadIdx.y;
  #pragma unroll
  for (int i = 0; i < 4; ++i)
    tile[ty + i * 8][tx] = W[lo + (long)(k0 + ty + i * 8) * N + n0 + tx];
  __syncthreads();
  #pragma unroll
  for (int i = 0; i < 4; ++i)
    Wt[lo + (long)(n0 + ty + i * 8) * K + k0 + tx] = f2bf(tile[tx][ty + i * 8]);
}

// ---------------------------------------------------------------------------
// V transpose: v bf16 [B,S,H,DH] -> Vt bf16 [B,H,DH,S]
// ---------------------------------------------------------------------------
__global__ void vtrans(const short* __restrict__ v, short* __restrict__ Vt)
{
  __shared__ short tile[32][33];
  int bh = blockIdx.z;
  int b = bh >> 4, h = bh & 15;
  int s0 = blockIdx.x * 32, d0 = blockIdx.y * 32;
  int tx = threadIdx.x, ty = threadIdx.y;
  #pragma unroll
  for (int i = 0; i < 4; ++i)
    tile[ty + i * 8][tx] = v[((long)(b * SEQL + s0 + ty + i * 8)) * DM + h * DH + d0 + tx];
  __syncthreads();
  #pragma unroll
  for (int i = 0; i < 4; ++i)
    Vt[((long)(bh * DH + d0 + ty + i * 8)) * SEQL + s0 + tx] = tile[tx][ty + i * 8];
}

// ---------------------------------------------------------------------------
static inline void launch_gemm(hipStream_t st, const short* A, const void* Bt, bool btf32,
    void* C, const float* bias, const float* resid,
    int M, int N, int K, int lda, int ldb, int ldc,
    long Asb, long Ash, long Bsb, long Bsh, long Csb, long Csh,
    int Hdiv, int Z, float alpha, int flags)
{
  dim3 grid((N + 127) / 128, (M + 127) / 128, Z), blk(256);
  if (btf32)
    gemm_bt<true><<<grid, blk, 0, st>>>(A, Bt, C, bias, resid, M, N, K, lda, ldb, ldc,
                                        Asb, Ash, Bsb, Bsh, Csb, Csh, Hdiv, alpha, flags);
  else
    gemm_bt<false><<<grid, blk, 0, st>>>(A, Bt, C, bias, resid, M, N, K, lda, ldb, ldc,
                                         Asb, Ash, Bsb, Bsh, Csb, Csh, Hdiv, alpha, flags);
}

extern "C" void kernel_launch(void* const* d_in, const int* in_sizes, int n_in,
                              void* d_out, int out_size, void* d_ws, size_t ws_size,
                              hipStream_t stream)
{
  (void)in_sizes; (void)n_in; (void)out_size;
  const int*   toks = (const int*)  d_in[0];
  const float* temb = (const float*)d_in[1];
  const float* pemb = (const float*)d_in[2];
  const float* Wq  = (const float*)d_in[3];  const float* bq  = (const float*)d_in[4];
  const float* Wk  = (const float*)d_in[5];  const float* bk  = (const float*)d_in[6];
  const float* Wv  = (const float*)d_in[7];  const float* bv  = (const float*)d_in[8];
  const float* Wo  = (const float*)d_in[9];  const float* bo  = (const float*)d_in[10];
  const float* g1  = (const float*)d_in[11]; const float* be1 = (const float*)d_in[12];
  const float* W1  = (const float*)d_in[13]; const float* bf1 = (const float*)d_in[14];
  const float* W2  = (const float*)d_in[15]; const float* bf2 = (const float*)d_in[16];
  const float* g2  = (const float*)d_in[17]; const float* be2 = (const float*)d_in[18];
  const float* gf  = (const float*)d_in[19]; const float* bfb = (const float*)d_in[20];

  char* p = (char*)d_ws;
  auto carve = [&](size_t bytes) -> char* {
    char* r = p;
    p += (bytes + 255) & ~(size_t)255;
    return r;
  };
  short* Wqt = (short*)carve((size_t)NLAYER * DM * DM * 2);
  short* Wkt = (short*)carve((size_t)NLAYER * DM * DM * 2);
  short* Wvt = (short*)carve((size_t)NLAYER * DM * DM * 2);
  short* Wot = (short*)carve((size_t)NLAYER * DM * DM * 2);
  short* W1t = (short*)carve((size_t)NLAYER * DM * DFFN * 2);
  short* W2t = (short*)carve((size_t)NLAYER * DM * DFFN * 2);
  float* x   = (float*)carve((size_t)TOKENS * DM * 4);
  short* h   = (short*)carve((size_t)TOKENS * DM * 2);
  short* qb  = (short*)carve((size_t)TOKENS * DM * 2);
  short* kb  = (short*)carve((size_t)TOKENS * DM * 2);
  short* vb  = (short*)carve((size_t)TOKENS * DM * 2);
  short* Vt  = (short*)carve((size_t)NBATCH * NHEAD * DH * SEQL * 2);
  short* Sc  = (short*)carve((size_t)NBATCH * NHEAD * SEQL * SEQL * 2);
  short* ffb = Sc;  // FFN hidden aliases score buffer (dead by then, rewritten next layer)
  short* attn= (short*)carve((size_t)TOKENS * DM * 2);
  if ((size_t)(p - (char*)d_ws) > ws_size) return;  // ws too small: clean fail

  dim3 tb(32, 8);

  embed_k<<<TOKENS, 256, 0, stream>>>(toks, temb, pemb, x);
  wtrans<<<dim3(DM / 32, DM / 32, NLAYER), tb, 0, stream>>>(Wq, Wqt, DM, DM);
  wtrans<<<dim3(DM / 32, DM / 32, NLAYER), tb, 0, stream>>>(Wk, Wkt, DM, DM);
  wtrans<<<dim3(DM / 32, DM / 32, NLAYER), tb, 0, stream>>>(Wv, Wvt, DM, DM);
  wtrans<<<dim3(DM / 32, DM / 32, NLAYER), tb, 0, stream>>>(Wo, Wot, DM, DM);
  wtrans<<<dim3(DFFN / 32, DM / 32, NLAYER), tb, 0, stream>>>(W1, W1t, DM, DFFN);
  wtrans<<<dim3(DM / 32, DFFN / 32, NLAYER), tb, 0, stream>>>(W2, W2t, DFFN, DM);

  for (int l = 0; l < NLAYER; ++l) {
    const size_t wdd = (size_t)l * DM * DM;
    const size_t wdf = (size_t)l * DM * DFFN;
    ln_bf16<<<TOKENS, 256, 0, stream>>>(x, g1 + l * DM, be1 + l * DM, h);
    launch_gemm(stream, h, Wqt + wdd, false, qb, bq + l * DM, nullptr,
                TOKENS, DM, DM, DM, DM, DM, 0, 0, 0, 0, 0, 0, 1, 1, 1.f, FLAG_OUTBF16);
    launch_gemm(stream, h, Wkt + wdd, false, kb, bk + l * DM, nullptr,
                TOKENS, DM, DM, DM, DM, DM, 0, 0, 0, 0, 0, 0, 1, 1, 1.f, FLAG_OUTBF16);
    launch_gemm(stream, h, Wvt + wdd, false, vb, bv + l * DM, nullptr,
                TOKENS, DM, DM, DM, DM, DM, 0, 0, 0, 0, 0, 0, 1, 1, 1.f, FLAG_OUTBF16);
    vtrans<<<dim3(SEQL / 32, DH / 32, NBATCH * NHEAD), tb, 0, stream>>>(vb, Vt);
    // scores = q k^T / sqrt(dk)  (batched over b,h; skip tiles above diagonal)
    launch_gemm(stream, qb, kb, false, Sc, nullptr, nullptr,
                SEQL, SEQL, DH, DM, DM, SEQL,
                (long)SEQL * DM, DH, (long)SEQL * DM, DH,
                (long)NHEAD * SEQL * SEQL, (long)SEQL * SEQL,
                NHEAD, NBATCH * NHEAD, 0.125f, FLAG_OUTBF16 | FLAG_CSKIP);
    softmax_causal<<<(NBATCH * NHEAD * SEQL) / 4, 256, 0, stream>>>(Sc);
    // attn = P @ V  (k-loop limited to causal extent)
    launch_gemm(stream, Sc, Vt, false, attn, nullptr, nullptr,
                SEQL, DH, SEQL, SEQL, SEQL, DM,
                (long)NHEAD * SEQL * SEQL, (long)SEQL * SEQL,
                (long)NHEAD * DH * SEQL, (long)DH * SEQL,
                (long)SEQL * DM, DH,
                NHEAD, NBATCH * NHEAD, 1.f, FLAG_OUTBF16 | FLAG_CKLIM);
    launch_gemm(stream, attn, Wot + wdd, false, x, bo + l * DM, x,
                TOKENS, DM, DM, DM, DM, DM, 0, 0, 0, 0, 0, 0, 1, 1, 1.f, 0);
    ln_bf16<<<TOKENS, 256, 0, stream>>>(x, g2 + l * DM, be2 + l * DM, h);
    launch_gemm(stream, h, W1t + wdf, false, ffb, bf1 + l * DFFN, nullptr,
                TOKENS, DFFN, DM, DM, DM, DFFN, 0, 0, 0, 0, 0, 0, 1, 1, 1.f,
                FLAG_OUTBF16 | FLAG_RELU);
    launch_gemm(stream, ffb, W2t + wdf, false, x, bf2 + l * DM, x,
                TOKENS, DM, DFFN, DFFN, DFFN, DM, 0, 0, 0, 0, 0, 0, 1, 1, 1.f, 0);
  }
  ln_bf16<<<TOKENS, 256, 0, stream>>>(x, gf, bfb, h);
  // logits = h @ tok_emb^T  (tok_emb already [N,K]; fp32 staged -> bf16)
  launch_gemm(stream, h, temb, true, d_out, nullptr, nullptr,
              TOKENS, NVOCAB, DM, DM, DM, NVOCAB, 0, 0, 0, 0, 0, 0, 1, 1, 1.f, 0);
}

// Round 2
// 1857.090 us; speedup vs baseline: 1.8445x; 1.8445x over previous
//
#include <hip/hip_runtime.h>

#define TOKENS 2048
#define DM 1024
#define NHEAD 16
#define DH 64
#define SEQL 512
#define NBATCH 4
#define DFFN 4096
#define NLAYER 6
#define NVOCAB 32000

typedef short short8 __attribute__((ext_vector_type(8)));
typedef short short4v __attribute__((ext_vector_type(4)));
typedef float floatx4 __attribute__((ext_vector_type(4)));

#define FLAG_RELU 1
#define FLAG_OUTBF16 2
#define FLAG_CSKIP 4
#define FLAG_CKLIM 8

__device__ __forceinline__ float bf2f(short s) {
  unsigned u = ((unsigned)(unsigned short)s) << 16;
  return __builtin_bit_cast(float, u);
}
__device__ __forceinline__ short f2bf(float f) {
  unsigned u = __builtin_bit_cast(unsigned, f);
  u = (u + 0x7FFFu + ((u >> 16) & 1u)) >> 16;
  return (short)(unsigned short)u;
}

// ---------------------------------------------------------------------------
// GEMM: C[M,N] = alpha * A[M,K](bf16) x Bt[N,K]^T(bf16)  (+bias +resid, relu)
// m97 structure: BK=32, linear LDS [rows][32] (64B rows), global_load_lds
// width-16 staging, 4 waves in WRxWC grid, per-wave (BM/WR)x(BN/WC) via
// 16x16x32 MFMA fragments. All M,N,K multiples of tile dims (no guards).
// XCD-bijective swizzle on flattened x/y grid when nwg%8==0.
// ---------------------------------------------------------------------------
template<int BM, int BN, int WR, int WC>
__global__ __launch_bounds__(256) void gemm_bt(
    const short* __restrict__ A, const short* __restrict__ Bt, void* __restrict__ Cv,
    const float* __restrict__ bias, const float* __restrict__ resid,
    int K, int lda, int ldb, int ldc,
    long A_sb, long A_sh, long B_sb, long B_sh, long C_sb, long C_sh,
    int Hdiv, float alpha, int flags)
{
  constexpr int FI = BM / WR / 16;
  constexpr int FJ = BN / WC / 16;
  __shared__ short As[BM * 32];
  __shared__ short Bs[BN * 32];

  const int gx = gridDim.x;
  int bid = blockIdx.y * gx + blockIdx.x;
  const int nwg = gx * gridDim.y;
  if ((nwg & 7) == 0) { const int cpx = nwg >> 3; bid = (bid & 7) * cpx + (bid >> 3); }
  const int row0 = (bid / gx) * BM, col0 = (bid % gx) * BN;
  if ((flags & FLAG_CSKIP) && col0 > row0 + BM - 1) return;

  const int z = blockIdx.z;
  const int bz = z / Hdiv, hz = z % Hdiv;
  const short* Ab = A + bz * A_sb + hz * A_sh;
  const short* Bb = Bt + bz * B_sb + hz * B_sh;
  const long coff = bz * C_sb + hz * C_sh;

  const int tid = threadIdx.x;
  const int lane = tid & 63;
  const int wid = tid >> 6;
  const int wr = wid / WC, wc = wid % WC;
  const int lc = lane & 15, g = lane >> 4;
  const int srow = lane >> 2, scol = (lane & 3) * 8;

  char* AsC = (char*)As;
  char* BsC = (char*)Bs;

  floatx4 acc[FI][FJ];
  #pragma unroll
  for (int i = 0; i < FI; ++i)
    #pragma unroll
    for (int j = 0; j < FJ; ++j)
      acc[i][j] = (floatx4){0.f, 0.f, 0.f, 0.f};

  int kmax = K;
  if (flags & FLAG_CKLIM) kmax = min(K, row0 + BM);

  for (int k0 = 0; k0 < kmax; k0 += 32) {
    #pragma unroll
    for (int it = 0; it < BM / 64; ++it) {
      const int seg = it * 4 + wid;
      const short* src = Ab + (long)(row0 + seg * 16 + srow) * lda + k0 + scol;
      __builtin_amdgcn_global_load_lds(
          (const __attribute__((address_space(1))) void*)src,
          (__attribute__((address_space(3))) void*)(AsC + seg * 1024), 16, 0, 0);
    }
    #pragma unroll
    for (int it = 0; it < BN / 64; ++it) {
      const int seg = it * 4 + wid;
      const short* src = Bb + (long)(col0 + seg * 16 + srow) * ldb + k0 + scol;
      __builtin_amdgcn_global_load_lds(
          (const __attribute__((address_space(1))) void*)src,
          (__attribute__((address_space(3))) void*)(BsC + seg * 1024), 16, 0, 0);
    }
    __syncthreads();

    short8 fa[FI], fb[FJ];
    #pragma unroll
    for (int i = 0; i < FI; ++i)
      fa[i] = *(const short8*)&As[(wr * (BM / WR) + i * 16 + lc) * 32 + g * 8];
    #pragma unroll
    for (int j = 0; j < FJ; ++j)
      fb[j] = *(const short8*)&Bs[(wc * (BN / WC) + j * 16 + lc) * 32 + g * 8];
    #pragma unroll
    for (int i = 0; i < FI; ++i)
      #pragma unroll
      for (int j = 0; j < FJ; ++j)
        acc[i][j] = __builtin_amdgcn_mfma_f32_16x16x32_bf16(fa[i], fb[j], acc[i][j], 0, 0, 0);
    __syncthreads();
  }

  const bool relu = flags & FLAG_RELU;
  const bool obf  = flags & FLAG_OUTBF16;
  float* Cf = (float*)Cv;
  short* Cb = (short*)Cv;
  #pragma unroll
  for (int i = 0; i < FI; ++i) {
    int orow = row0 + wr * (BM / WR) + i * 16 + g * 4;  // C/D: row = 4*(lane>>4)+t
    #pragma unroll
    for (int j = 0; j < FJ; ++j) {
      int ocol = col0 + wc * (BN / WC) + j * 16 + lc;   // C/D: col = lane&15
      #pragma unroll
      for (int t = 0; t < 4; ++t) {
        long off = coff + (long)(orow + t) * ldc + ocol;
        float v = alpha * acc[i][j][t];
        if (bias)  v += bias[ocol];
        if (resid) v += resid[off];
        if (relu)  v = fmaxf(v, 0.f);
        if (obf) Cb[off] = f2bf(v); else Cf[off] = v;
      }
    }
  }
}

template<int BM, int BN, int WR, int WC>
static inline void launch_gemm(hipStream_t st, const short* A, const short* Bt, void* C,
    const float* bias, const float* resid, int M, int N, int K,
    int lda, int ldb, int ldc,
    long Asb, long Ash, long Bsb, long Bsh, long Csb, long Csh,
    int Hdiv, int Z, float alpha, int flags)
{
  dim3 grid(N / BN, M / BM, Z), blk(256);
  gemm_bt<BM, BN, WR, WC><<<grid, blk, 0, st>>>(A, Bt, C, bias, resid, K, lda, ldb, ldc,
      Asb, Ash, Bsb, Bsh, Csb, Csh, Hdiv, alpha, flags);
}

// ---------------------------------------------------------------------------
// LayerNorm (population std, /(std+eps)) fp32 in -> bf16 out. 1 block per row.
// ---------------------------------------------------------------------------
__global__ __launch_bounds__(256) void ln_bf16(const float* __restrict__ x,
    const float* __restrict__ gg, const float* __restrict__ bb, short* __restrict__ out)
{
  int row = blockIdx.x;
  const float4 u = ((const float4*)(x + (long)row * DM))[threadIdx.x];
  float s  = u.x + u.y + u.z + u.w;
  float sq = u.x * u.x + u.y * u.y + u.z * u.z + u.w * u.w;
  #pragma unroll
  for (int o = 32; o; o >>= 1) { s += __shfl_xor(s, o); sq += __shfl_xor(sq, o); }
  __shared__ float red[8];
  int lane = threadIdx.x & 63, wid = threadIdx.x >> 6;
  if (lane == 0) { red[wid] = s; red[4 + wid] = sq; }
  __syncthreads();
  s  = red[0] + red[1] + red[2] + red[3];
  sq = red[4] + red[5] + red[6] + red[7];
  float mu  = s * (1.f / DM);
  float var = fmaxf(sq * (1.f / DM) - mu * mu, 0.f);
  float inv = 1.f / (sqrtf(var) + 1e-6f);
  int c = threadIdx.x * 4;
  const float4 gv = ((const float4*)gg)[threadIdx.x];
  const float4 bv = ((const float4*)bb)[threadIdx.x];
  short4v o;
  o[0] = f2bf((u.x - mu) * inv * gv.x + bv.x);
  o[1] = f2bf((u.y - mu) * inv * gv.y + bv.y);
  o[2] = f2bf((u.z - mu) * inv * gv.z + bv.z);
  o[3] = f2bf((u.w - mu) * inv * gv.w + bv.w);
  *(short4v*)(out + (long)row * DM + c) = o;
}

// ---------------------------------------------------------------------------
__global__ __launch_bounds__(256) void embed_k(const int* __restrict__ toks,
    const float* __restrict__ emb, const float* __restrict__ pos, float* __restrict__ x)
{
  int row = blockIdx.x;
  int s = row & (SEQL - 1);
  long tk = toks[row];
  const float4 e = ((const float4*)(emb + tk * DM))[threadIdx.x];
  const float4 p = ((const float4*)(pos + (long)s * DM))[threadIdx.x];
  float4 o;
  o.x = e.x * 32.f + p.x; o.y = e.y * 32.f + p.y;
  o.z = e.z * 32.f + p.z; o.w = e.w * 32.f + p.w;
  ((float4*)(x + (long)row * DM))[threadIdx.x] = o;
}

// ---------------------------------------------------------------------------
// Causal softmax in-place on bf16 scores [B*H*S, S]; one wave per row.
// ---------------------------------------------------------------------------
__global__ __launch_bounds__(256) void softmax_causal(short* __restrict__ Sc)
{
  int wid = threadIdx.x >> 6, lane = threadIdx.x & 63;
  long row = (long)blockIdx.x * 4 + wid;
  int q = (int)(row & (SEQL - 1));
  short8* rp = (short8*)(Sc + row * SEQL);
  short8 v = rp[lane];
  int base = lane * 8;
  float f[8], mx = -3e38f;
  #pragma unroll
  for (int e = 0; e < 8; ++e) {
    f[e] = (base + e <= q) ? bf2f(v[e]) : -3e38f;
    mx = fmaxf(mx, f[e]);
  }
  #pragma unroll
  for (int o = 32; o; o >>= 1) mx = fmaxf(mx, __shfl_xor(mx, o));
  float sum = 0.f;
  #pragma unroll
  for (int e = 0; e < 8; ++e) {
    float p = (base + e <= q) ? __expf(f[e] - mx) : 0.f;
    f[e] = p; sum += p;
  }
  #pragma unroll
  for (int o = 32; o; o >>= 1) sum += __shfl_xor(sum, o);
  float inv = 1.f / sum;
  short8 o8;
  #pragma unroll
  for (int e = 0; e < 8; ++e) o8[e] = f2bf(f[e] * inv);
  rp[lane] = o8;
}

// ---------------------------------------------------------------------------
// Weight transpose+convert: W fp32 [z][K][N] -> Wt bf16 [z (stride zsout)][N][K]
// ---------------------------------------------------------------------------
__global__ void wtrans(const float* __restrict__ W, short* __restrict__ Wt,
                       int K, int N, long zsout)
{
  __shared__ float tile[32][33];
  const long lo = (long)blockIdx.z * K * N;
  const long oo = (long)blockIdx.z * zsout;
  int n0 = blockIdx.x * 32, k0 = blockIdx.y * 32;
  int tx = threadIdx.x, ty = threadIdx.y;
  #pragma unroll
  for (int i = 0; i < 4; ++i)
    tile[ty + i * 8][tx] = W[lo + (long)(k0 + ty + i * 8) * N + n0 + tx];
  __syncthreads();
  #pragma unroll
  for (int i = 0; i < 4; ++i)
    Wt[oo + (long)(n0 + ty + i * 8) * K + k0 + tx] = f2bf(tile[tx][ty + i * 8]);
}

// ---------------------------------------------------------------------------
// fp32 -> bf16 bulk convert (no transpose), 8 elems/thread
// ---------------------------------------------------------------------------
__global__ __launch_bounds__(256) void conv_bf16(const float* __restrict__ in,
                                                 short* __restrict__ out)
{
  long i = ((long)blockIdx.x * 256 + threadIdx.x) * 8;
  float4 a = *(const float4*)(in + i);
  float4 b = *(const float4*)(in + i + 4);
  short8 o;
  o[0] = f2bf(a.x); o[1] = f2bf(a.y); o[2] = f2bf(a.z); o[3] = f2bf(a.w);
  o[4] = f2bf(b.x); o[5] = f2bf(b.y); o[6] = f2bf(b.z); o[7] = f2bf(b.w);
  *(short8*)(out + i) = o;
}

// ---------------------------------------------------------------------------
// V transpose: v bf16 rows of fused qkv [B*S][3072] (v at col 2048) -> Vt [B,H,DH,S]
// ---------------------------------------------------------------------------
__global__ void vtrans(const short* __restrict__ qkv, short* __restrict__ Vt)
{
  __shared__ short tile[32][33];
  int bh = blockIdx.z;
  int b = bh >> 4, h = bh & 15;
  int s0 = blockIdx.x * 32, d0 = blockIdx.y * 32;
  int tx = threadIdx.x, ty = threadIdx.y;
  #pragma unroll
  for (int i = 0; i < 4; ++i)
    tile[ty + i * 8][tx] =
        qkv[((long)(b * SEQL + s0 + ty + i * 8)) * 3072 + 2048 + h * DH + d0 + tx];
  __syncthreads();
  #pragma unroll
  for (int i = 0; i < 4; ++i)
    Vt[((long)(bh * DH + d0 + ty + i * 8)) * SEQL + s0 + tx] = tile[tx][ty + i * 8];
}

// ---------------------------------------------------------------------------
__global__ void bias_cat(const float* __restrict__ bq, const float* __restrict__ bk,
                         const float* __restrict__ bv, float* __restrict__ out)
{
  int l = blockIdx.y;
  int i = blockIdx.x * 256 + threadIdx.x;  // 0..3071
  float v = (i < 1024) ? bq[l * 1024 + i]
          : (i < 2048) ? bk[l * 1024 + i - 1024]
                       : bv[l * 1024 + i - 2048];
  out[(long)l * 3072 + i] = v;
}

// ---------------------------------------------------------------------------
extern "C" void kernel_launch(void* const* d_in, const int* in_sizes, int n_in,
                              void* d_out, int out_size, void* d_ws, size_t ws_size,
                              hipStream_t stream)
{
  (void)in_sizes; (void)n_in; (void)out_size;
  const int*   toks = (const int*)  d_in[0];
  const float* temb = (const float*)d_in[1];
  const float* pemb = (const float*)d_in[2];
  const float* Wq  = (const float*)d_in[3];  const float* bq  = (const float*)d_in[4];
  const float* Wk  = (const float*)d_in[5];  const float* bk  = (const float*)d_in[6];
  const float* Wv  = (const float*)d_in[7];  const float* bv  = (const float*)d_in[8];
  const float* Wo  = (const float*)d_in[9];  const float* bo  = (const float*)d_in[10];
  const float* g1  = (const float*)d_in[11]; const float* be1 = (const float*)d_in[12];
  const float* W1  = (const float*)d_in[13]; const float* bf1 = (const float*)d_in[14];
  const float* W2  = (const float*)d_in[15]; const float* bf2 = (const float*)d_in[16];
  const float* g2  = (const float*)d_in[17]; const float* be2 = (const float*)d_in[18];
  const float* gf  = (const float*)d_in[19]; const float* bfb = (const float*)d_in[20];

  char* p = (char*)d_ws;
  auto carve = [&](size_t bytes) -> char* {
    char* r = p;
    p += (bytes + 255) & ~(size_t)255;
    return r;
  };
  // h survives to the head GEMM; everything after it is dead by then and is
  // aliased by tembb (bf16 tok_emb), converted AFTER the final layernorm.
  short* h     = (short*)carve((size_t)TOKENS * DM * 2);
  char*  uni   = p;
  short* tembb = (short*)uni;  // 32000*1024*2 = 65.5 MB, overlaps region below
  short* Wqkvt = (short*)carve((size_t)NLAYER * 3072 * DM * 2);
  short* Wot   = (short*)carve((size_t)NLAYER * DM * DM * 2);
  short* W1t   = (short*)carve((size_t)NLAYER * DM * DFFN * 2);
  short* W2t   = (short*)carve((size_t)NLAYER * DM * DFFN * 2);
  float* x     = (float*)carve((size_t)TOKENS * DM * 4);
  short* qkv   = (short*)carve((size_t)TOKENS * 3072 * 2);
  short* attn  = qkv;  // PV output aliases dead q region (4.2 MB <= 12.6 MB)
  short* Vt    = (short*)carve((size_t)NBATCH * NHEAD * DH * SEQL * 2);
  short* Sc    = (short*)carve((size_t)NBATCH * NHEAD * SEQL * SEQL * 2);
  short* ffb   = Sc;   // FFN hidden aliases dead score buffer
  float* bqkv  = (float*)carve((size_t)NLAYER * 3072 * 4);
  size_t used = (size_t)(p - (char*)d_ws);
  size_t need_t = (size_t)(uni - (char*)d_ws) + (size_t)NVOCAB * DM * 2;
  if (used > ws_size || need_t > ws_size) return;  // ws too small: clean fail

  dim3 tb(32, 8);

  embed_k<<<TOKENS, 256, 0, stream>>>(toks, temb, pemb, x);
  bias_cat<<<dim3(12, NLAYER), 256, 0, stream>>>(bq, bk, bv, bqkv);
  // Wq/Wk/Wv transpose into fused [L][3072][1024] (col-blocks q,k,v)
  wtrans<<<dim3(DM / 32, DM / 32, NLAYER), tb, 0, stream>>>(Wq, Wqkvt, DM, DM, 3072L * DM);
  wtrans<<<dim3(DM / 32, DM / 32, NLAYER), tb, 0, stream>>>(Wk, Wqkvt + (size_t)DM * DM, DM, DM, 3072L * DM);
  wtrans<<<dim3(DM / 32, DM / 32, NLAYER), tb, 0, stream>>>(Wv, Wqkvt + (size_t)2 * DM * DM, DM, DM, 3072L * DM);
  wtrans<<<dim3(DM / 32, DM / 32, NLAYER), tb, 0, stream>>>(Wo, Wot, DM, DM, (long)DM * DM);
  wtrans<<<dim3(DFFN / 32, DM / 32, NLAYER), tb, 0, stream>>>(W1, W1t, DM, DFFN, (long)DM * DFFN);
  wtrans<<<dim3(DM / 32, DFFN / 32, NLAYER), tb, 0, stream>>>(W2, W2t, DFFN, DM, (long)DM * DFFN);

  for (int l = 0; l < NLAYER; ++l) {
    const size_t wqkv = (size_t)l * 3072 * DM;
    const size_t wdd  = (size_t)l * DM * DM;
    const size_t wdf  = (size_t)l * DM * DFFN;
    ln_bf16<<<TOKENS, 256, 0, stream>>>(x, g1 + l * DM, be1 + l * DM, h);
    // fused QKV: [2048,1024] x [3072,1024]^T -> qkv [2048,3072]
    launch_gemm<128, 128, 2, 2>(stream, h, Wqkvt + wqkv, qkv, bqkv + (size_t)l * 3072,
        nullptr, TOKENS, 3072, DM, DM, DM, 3072, 0, 0, 0, 0, 0, 0, 1, 1, 1.f, FLAG_OUTBF16);
    vtrans<<<dim3(SEQL / 32, DH / 32, NBATCH * NHEAD), tb, 0, stream>>>(qkv, Vt);
    // scores = q k^T / sqrt(dk)  (q at col 0, k at col 1024 of qkv)
    launch_gemm<128, 128, 2, 2>(stream, qkv, qkv + 1024, Sc, nullptr, nullptr,
        SEQL, SEQL, DH, 3072, 3072, SEQL,
        (long)SEQL * 3072, DH, (long)SEQL * 3072, DH,
        (long)NHEAD * SEQL * SEQL, (long)SEQL * SEQL,
        NHEAD, NBATCH * NHEAD, 0.125f, FLAG_OUTBF16 | FLAG_CSKIP);
    softmax_causal<<<(NBATCH * NHEAD * SEQL) / 4, 256, 0, stream>>>(Sc);
    // attn = P @ V  (k-loop limited to causal extent); attn aliases dead q region
    launch_gemm<128, 64, 2, 2>(stream, Sc, Vt, attn, nullptr, nullptr,
        SEQL, DH, SEQL, SEQL, SEQL, DM,
        (long)NHEAD * SEQL * SEQL, (long)SEQL * SEQL,
        (long)NHEAD * DH * SEQL, (long)DH * SEQL,
        (long)SEQL * DM, DH,
        NHEAD, NBATCH * NHEAD, 1.f, FLAG_OUTBF16 | FLAG_CKLIM);
    launch_gemm<64, 128, 1, 4>(stream, attn, Wot + wdd, x, bo + l * DM, x,
        TOKENS, DM, DM, DM, DM, DM, 0, 0, 0, 0, 0, 0, 1, 1, 1.f, 0);
    ln_bf16<<<TOKENS, 256, 0, stream>>>(x, g2 + l * DM, be2 + l * DM, h);
    launch_gemm<128, 128, 2, 2>(stream, h, W1t + wdf, ffb, bf1 + l * DFFN, nullptr,
        TOKENS, DFFN, DM, DM, DM, DFFN, 0, 0, 0, 0, 0, 0, 1, 1, 1.f,
        FLAG_OUTBF16 | FLAG_RELU);
    launch_gemm<64, 128, 1, 4>(stream, ffb, W2t + wdf, x, bf2 + l * DM, x,
        TOKENS, DM, DFFN, DFFN, DFFN, DM, 0, 0, 0, 0, 0, 0, 1, 1, 1.f, 0);
  }
  ln_bf16<<<TOKENS, 256, 0, stream>>>(x, gf, bfb, h);
  // convert tok_emb fp32 -> bf16 (overlaps now-dead weight buffers)
  conv_bf16<<<(NVOCAB * DM) / (256 * 8), 256, 0, stream>>>(temb, tembb);
  // logits = h @ tembb^T
  launch_gemm<128, 128, 2, 2>(stream, h, tembb, d_out, nullptr, nullptr,
      TOKENS, NVOCAB, DM, DM, DM, NVOCAB, 0, 0, 0, 0, 0, 0, 1, 1, 1.f, 0);
}

// Round 3
// 1707.809 us; speedup vs baseline: 2.0058x; 1.0874x over previous
//
#include <hip/hip_runtime.h>

#define TOKENS 2048
#define DM 1024
#define NHEAD 16
#define DH 64
#define SEQL 512
#define NBATCH 4
#define DFFN 4096
#define NLAYER 6
#define NVOCAB 32000

typedef short short8 __attribute__((ext_vector_type(8)));
typedef short short4v __attribute__((ext_vector_type(4)));
typedef float floatx4 __attribute__((ext_vector_type(4)));

#define FLAG_RELU 1
#define FLAG_OUTBF16 2

__device__ __forceinline__ float bf2f(short s) {
  unsigned u = ((unsigned)(unsigned short)s) << 16;
  return __builtin_bit_cast(float, u);
}
__device__ __forceinline__ short f2bf(float f) {
  unsigned u = __builtin_bit_cast(unsigned, f);
  u = (u + 0x7FFFu + ((u >> 16) & 1u)) >> 16;
  return (short)(unsigned short)u;
}

// ---------------------------------------------------------------------------
// GEMM: C[M,N] = alpha * A[M,K](bf16) x Bt[N,K]^T(bf16)  (+bias +resid, relu)
// m97 structure: BK=32, linear LDS [rows][32], global_load_lds width-16,
// 4 waves WRxWC, 16x16x32 MFMA fragments. XCD-bijective swizzle.
// ---------------------------------------------------------------------------
template<int BM, int BN, int WR, int WC>
__global__ __launch_bounds__(256) void gemm_bt(
    const short* __restrict__ A, const short* __restrict__ Bt, void* __restrict__ Cv,
    const float* __restrict__ bias, const float* __restrict__ resid,
    int K, int lda, int ldb, int ldc, float alpha, int flags)
{
  constexpr int FI = BM / WR / 16;
  constexpr int FJ = BN / WC / 16;
  __shared__ short As[BM * 32];
  __shared__ short Bs[BN * 32];

  const int gx = gridDim.x;
  int bid = blockIdx.y * gx + blockIdx.x;
  const int nwg = gx * gridDim.y;
  if ((nwg & 7) == 0) { const int cpx = nwg >> 3; bid = (bid & 7) * cpx + (bid >> 3); }
  const int row0 = (bid / gx) * BM, col0 = (bid % gx) * BN;

  const int tid = threadIdx.x;
  const int lane = tid & 63;
  const int wid = tid >> 6;
  const int wr = wid / WC, wc = wid % WC;
  const int lc = lane & 15, g = lane >> 4;
  const int srow = lane >> 2, scol = (lane & 3) * 8;

  char* AsC = (char*)As;
  char* BsC = (char*)Bs;

  floatx4 acc[FI][FJ];
  #pragma unroll
  for (int i = 0; i < FI; ++i)
    #pragma unroll
    for (int j = 0; j < FJ; ++j)
      acc[i][j] = (floatx4){0.f, 0.f, 0.f, 0.f};

  for (int k0 = 0; k0 < K; k0 += 32) {
    #pragma unroll
    for (int it = 0; it < BM / 64; ++it) {
      const int seg = it * 4 + wid;
      const short* src = A + (long)(row0 + seg * 16 + srow) * lda + k0 + scol;
      __builtin_amdgcn_global_load_lds(
          (const __attribute__((address_space(1))) void*)src,
          (__attribute__((address_space(3))) void*)(AsC + seg * 1024), 16, 0, 0);
    }
    #pragma unroll
    for (int it = 0; it < BN / 64; ++it) {
      const int seg = it * 4 + wid;
      const short* src = Bt + (long)(col0 + seg * 16 + srow) * ldb + k0 + scol;
      __builtin_amdgcn_global_load_lds(
          (const __attribute__((address_space(1))) void*)src,
          (__attribute__((address_space(3))) void*)(BsC + seg * 1024), 16, 0, 0);
    }
    __syncthreads();

    short8 fa[FI], fb[FJ];
    #pragma unroll
    for (int i = 0; i < FI; ++i)
      fa[i] = *(const short8*)&As[(wr * (BM / WR) + i * 16 + lc) * 32 + g * 8];
    #pragma unroll
    for (int j = 0; j < FJ; ++j)
      fb[j] = *(const short8*)&Bs[(wc * (BN / WC) + j * 16 + lc) * 32 + g * 8];
    #pragma unroll
    for (int i = 0; i < FI; ++i)
      #pragma unroll
      for (int j = 0; j < FJ; ++j)
        acc[i][j] = __builtin_amdgcn_mfma_f32_16x16x32_bf16(fa[i], fb[j], acc[i][j], 0, 0, 0);
    __syncthreads();
  }

  const bool relu = flags & FLAG_RELU;
  const bool obf  = flags & FLAG_OUTBF16;
  float* Cf = (float*)Cv;
  short* Cb = (short*)Cv;
  #pragma unroll
  for (int i = 0; i < FI; ++i) {
    int orow = row0 + wr * (BM / WR) + i * 16 + g * 4;
    #pragma unroll
    for (int j = 0; j < FJ; ++j) {
      int ocol = col0 + wc * (BN / WC) + j * 16 + lc;
      #pragma unroll
      for (int t = 0; t < 4; ++t) {
        long off = (long)(orow + t) * ldc + ocol;
        float v = alpha * acc[i][j][t];
        if (bias)  v += bias[ocol];
        if (resid) v += resid[off];
        if (relu)  v = fmaxf(v, 0.f);
        if (obf) Cb[off] = f2bf(v); else Cf[off] = v;
      }
    }
  }
}

template<int BM, int BN, int WR, int WC>
static inline void launch_gemm(hipStream_t st, const short* A, const short* Bt, void* C,
    const float* bias, const float* resid, int M, int N, int K,
    int lda, int ldb, int ldc, float alpha, int flags)
{
  dim3 grid(N / BN, M / BM, 1), blk(256);
  gemm_bt<BM, BN, WR, WC><<<grid, blk, 0, st>>>(A, Bt, C, bias, resid, K, lda, ldb, ldc,
                                                alpha, flags);
}

// ---------------------------------------------------------------------------
// Flash attention: per block = (q-tile of 64 rows, one (b,h)). 4 waves, each
// owns 16 q rows. KVBLK=64, online softmax. K/Vt tiles staged via
// global_load_lds with pre-swizzled source (chunk ^= row&7), reads XOR'd the
// same way. P round-trips via wave-private LDS tile (layout change S->A frag).
// ---------------------------------------------------------------------------
__global__ __launch_bounds__(256) void flash_attn(
    const short* __restrict__ qkv, const short* __restrict__ Vt,
    short* __restrict__ attn)
{
  const int qt = blockIdx.x;
  const int bh = blockIdx.y;
  const int b = bh >> 4, h = bh & 15;
  const int row0 = qt * 64;

  __shared__ short Kt[64 * 64];
  __shared__ short Vtl[64 * 64];
  __shared__ short Pt[4 * 16 * 64];

  const int tid = threadIdx.x;
  const int lane = tid & 63;
  const int wid = tid >> 6;
  const int lc = lane & 15, g = lane >> 4;

  // Q fragments, held in registers for the whole kernel
  short8 qf[2];
  {
    const short* qp = qkv + (long)(b * SEQL + row0 + wid * 16 + lc) * 3072 + h * DH;
    qf[0] = *(const short8*)(qp + g * 8);
    qf[1] = *(const short8*)(qp + 32 + g * 8);
  }

  floatx4 o[4];
  float m[4], l[4];
  #pragma unroll
  for (int j = 0; j < 4; ++j) o[j] = (floatx4){0.f, 0.f, 0.f, 0.f};
  #pragma unroll
  for (int t = 0; t < 4; ++t) { m[t] = -3e38f; l[t] = 0.f; }

  for (int kv0 = 0; kv0 <= row0; kv0 += 64) {
    // stage K [kv][d] and Vt-slice [d][kv], source chunk pre-swizzled
    #pragma unroll
    for (int i = 0; i < 2; ++i) {
      const int idx = i * 256 + tid;
      const int r = idx >> 3, cc = idx & 7;
      const int sw = cc ^ (r & 7);
      const short* ks = qkv + (long)(b * SEQL + kv0 + r) * 3072 + 1024 + h * DH + sw * 8;
      __builtin_amdgcn_global_load_lds(
          (const __attribute__((address_space(1))) void*)ks,
          (__attribute__((address_space(3))) void*)((char*)Kt + (i * 256 + wid * 64) * 16),
          16, 0, 0);
      const short* vs = Vt + (long)bh * DH * SEQL + (long)r * SEQL + kv0 + sw * 8;
      __builtin_amdgcn_global_load_lds(
          (const __attribute__((address_space(1))) void*)vs,
          (__attribute__((address_space(3))) void*)((char*)Vtl + (i * 256 + wid * 64) * 16),
          16, 0, 0);
    }
    __syncthreads();

    // S = Q K^T for this wave's 16 rows x 64 kv cols
    floatx4 s[4];
    #pragma unroll
    for (int j = 0; j < 4; ++j) s[j] = (floatx4){0.f, 0.f, 0.f, 0.f};
    #pragma unroll
    for (int ks_ = 0; ks_ < 2; ++ks_) {
      #pragma unroll
      for (int j = 0; j < 4; ++j) {
        const int row = j * 16 + lc;
        const short8 kf = *(const short8*)&Kt[row * 64 + ((ks_ * 4 + g) ^ (row & 7)) * 8];
        s[j] = __builtin_amdgcn_mfma_f32_16x16x32_bf16(qf[ks_], kf, s[j], 0, 0, 0);
      }
    }

    // online softmax; lane holds rows g*4+t, cols j*16+lc
    const bool diag = (kv0 == row0);
    float p[4][4], rmax[4], rsum[4], fs[4];
    #pragma unroll
    for (int t = 0; t < 4; ++t) rmax[t] = -3e38f;
    #pragma unroll
    for (int j = 0; j < 4; ++j)
      #pragma unroll
      for (int t = 0; t < 4; ++t) {
        float sv = s[j][t] * 0.125f;
        if (diag && (j * 16 + lc) > (wid * 16 + g * 4 + t)) sv = -3e38f;
        p[j][t] = sv;
        rmax[t] = fmaxf(rmax[t], sv);
      }
    #pragma unroll
    for (int t = 0; t < 4; ++t) {
      #pragma unroll
      for (int mk = 1; mk < 16; mk <<= 1)
        rmax[t] = fmaxf(rmax[t], __shfl_xor(rmax[t], mk));
      float mn = fmaxf(m[t], rmax[t]);
      fs[t] = __expf(m[t] - mn);
      m[t] = mn;
    }
    #pragma unroll
    for (int j = 0; j < 4; ++j)
      #pragma unroll
      for (int t = 0; t < 4; ++t)
        p[j][t] = __expf(p[j][t] - m[t]);
    #pragma unroll
    for (int t = 0; t < 4; ++t) {
      rsum[t] = p[0][t] + p[1][t] + p[2][t] + p[3][t];
      #pragma unroll
      for (int mk = 1; mk < 16; mk <<= 1)
        rsum[t] += __shfl_xor(rsum[t], mk);
      l[t] = l[t] * fs[t] + rsum[t];
    }
    #pragma unroll
    for (int j = 0; j < 4; ++j) {
      o[j][0] *= fs[0]; o[j][1] *= fs[1]; o[j][2] *= fs[2]; o[j][3] *= fs[3];
    }
    // write P into wave-private LDS tile [16 rows][64 kv], swizzled
    #pragma unroll
    for (int j = 0; j < 4; ++j)
      #pragma unroll
      for (int t = 0; t < 4; ++t) {
        const int r = g * 4 + t;
        const int col = j * 16 + lc;
        Pt[wid * 1024 + r * 64 + (((col >> 3) ^ (r & 7)) * 8) + (col & 7)] = f2bf(p[j][t]);
      }
    __syncthreads();

    // O += P V  (A = P rows q, B = Vtl rows d)
    #pragma unroll
    for (int ks_ = 0; ks_ < 2; ++ks_) {
      const short8 pf = *(const short8*)&Pt[wid * 1024 + lc * 64 + ((ks_ * 4 + g) ^ (lc & 7)) * 8];
      #pragma unroll
      for (int j = 0; j < 4; ++j) {
        const int row = j * 16 + lc;
        const short8 vf = *(const short8*)&Vtl[row * 64 + ((ks_ * 4 + g) ^ (row & 7)) * 8];
        o[j] = __builtin_amdgcn_mfma_f32_16x16x32_bf16(pf, vf, o[j], 0, 0, 0);
      }
    }
    __syncthreads();  // protect K/Vtl/Pt before next iteration's staging
  }

  float linv[4];
  #pragma unroll
  for (int t = 0; t < 4; ++t) linv[t] = 1.f / l[t];
  #pragma unroll
  for (int j = 0; j < 4; ++j)
    #pragma unroll
    for (int t = 0; t < 4; ++t) {
      const long row = (long)(b * SEQL + row0 + wid * 16 + g * 4 + t);
      attn[row * DM + h * DH + j * 16 + lc] = f2bf(o[j][t] * linv[t]);
    }
}

// ---------------------------------------------------------------------------
// LayerNorm (population std, /(std+eps)) fp32 in -> bf16 out. 1 block per row.
// ---------------------------------------------------------------------------
__global__ __launch_bounds__(256) void ln_bf16(const float* __restrict__ x,
    const float* __restrict__ gg, const float* __restrict__ bb, short* __restrict__ out)
{
  int row = blockIdx.x;
  const float4 u = ((const float4*)(x + (long)row * DM))[threadIdx.x];
  float s  = u.x + u.y + u.z + u.w;
  float sq = u.x * u.x + u.y * u.y + u.z * u.z + u.w * u.w;
  #pragma unroll
  for (int o = 32; o; o >>= 1) { s += __shfl_xor(s, o); sq += __shfl_xor(sq, o); }
  __shared__ float red[8];
  int lane = threadIdx.x & 63, wid = threadIdx.x >> 6;
  if (lane == 0) { red[wid] = s; red[4 + wid] = sq; }
  __syncthreads();
  s  = red[0] + red[1] + red[2] + red[3];
  sq = red[4] + red[5] + red[6] + red[7];
  float mu  = s * (1.f / DM);
  float var = fmaxf(sq * (1.f / DM) - mu * mu, 0.f);
  float inv = 1.f / (sqrtf(var) + 1e-6f);
  int c = threadIdx.x * 4;
  const float4 gv = ((const float4*)gg)[threadIdx.x];
  const float4 bv = ((const float4*)bb)[threadIdx.x];
  short4v o;
  o[0] = f2bf((u.x - mu) * inv * gv.x + bv.x);
  o[1] = f2bf((u.y - mu) * inv * gv.y + bv.y);
  o[2] = f2bf((u.z - mu) * inv * gv.z + bv.z);
  o[3] = f2bf((u.w - mu) * inv * gv.w + bv.w);
  *(short4v*)(out + (long)row * DM + c) = o;
}

// ---------------------------------------------------------------------------
__global__ __launch_bounds__(256) void embed_k(const int* __restrict__ toks,
    const float* __restrict__ emb, const float* __restrict__ pos, float* __restrict__ x)
{
  int row = blockIdx.x;
  int s = row & (SEQL - 1);
  long tk = toks[row];
  const float4 e = ((const float4*)(emb + tk * DM))[threadIdx.x];
  const float4 p = ((const float4*)(pos + (long)s * DM))[threadIdx.x];
  float4 o;
  o.x = e.x * 32.f + p.x; o.y = e.y * 32.f + p.y;
  o.z = e.z * 32.f + p.z; o.w = e.w * 32.f + p.w;
  ((float4*)(x + (long)row * DM))[threadIdx.x] = o;
}

// ---------------------------------------------------------------------------
// Weight transpose+convert: W fp32 [z][K][N] -> Wt bf16 [z (stride zsout)][N][K]
// ---------------------------------------------------------------------------
__global__ void wtrans(const float* __restrict__ W, short* __restrict__ Wt,
                       int K, int N, long zsout)
{
  __shared__ float tile[32][33];
  const long lo = (long)blockIdx.z * K * N;
  const long oo = (long)blockIdx.z * zsout;
  int n0 = blockIdx.x * 32, k0 = blockIdx.y * 32;
  int tx = threadIdx.x, ty = threadIdx.y;
  #pragma unroll
  for (int i = 0; i < 4; ++i)
    tile[ty + i * 8][tx] = W[lo + (long)(k0 + ty + i * 8) * N + n0 + tx];
  __syncthreads();
  #pragma unroll
  for (int i = 0; i < 4; ++i)
    Wt[oo + (long)(n0 + ty + i * 8) * K + k0 + tx] = f2bf(tile[tx][ty + i * 8]);
}

// ---------------------------------------------------------------------------
__global__ __launch_bounds__(256) void conv_bf16(const float* __restrict__ in,
                                                 short* __restrict__ out)
{
  long i = ((long)blockIdx.x * 256 + threadIdx.x) * 8;
  float4 a = *(const float4*)(in + i);
  float4 b = *(const float4*)(in + i + 4);
  short8 o;
  o[0] = f2bf(a.x); o[1] = f2bf(a.y); o[2] = f2bf(a.z); o[3] = f2bf(a.w);
  o[4] = f2bf(b.x); o[5] = f2bf(b.y); o[6] = f2bf(b.z); o[7] = f2bf(b.w);
  *(short8*)(out + i) = o;
}

// ---------------------------------------------------------------------------
// V transpose: v cols of fused qkv [B*S][3072] (v at col 2048) -> Vt [B,H,DH,S]
// ---------------------------------------------------------------------------
__global__ void vtrans(const short* __restrict__ qkv, short* __restrict__ Vt)
{
  __shared__ short tile[32][33];
  int bh = blockIdx.z;
  int b = bh >> 4, h = bh & 15;
  int s0 = blockIdx.x * 32, d0 = blockIdx.y * 32;
  int tx = threadIdx.x, ty = threadIdx.y;
  #pragma unroll
  for (int i = 0; i < 4; ++i)
    tile[ty + i * 8][tx] =
        qkv[((long)(b * SEQL + s0 + ty + i * 8)) * 3072 + 2048 + h * DH + d0 + tx];
  __syncthreads();
  #pragma unroll
  for (int i = 0; i < 4; ++i)
    Vt[((long)(bh * DH + d0 + ty + i * 8)) * SEQL + s0 + tx] = tile[tx][ty + i * 8];
}

// ---------------------------------------------------------------------------
__global__ void bias_cat(const float* __restrict__ bq, const float* __restrict__ bk,
                         const float* __restrict__ bv, float* __restrict__ out)
{
  int l = blockIdx.y;
  int i = blockIdx.x * 256 + threadIdx.x;
  float v = (i < 1024) ? bq[l * 1024 + i]
          : (i < 2048) ? bk[l * 1024 + i - 1024]
                       : bv[l * 1024 + i - 2048];
  out[(long)l * 3072 + i] = v;
}

// ---------------------------------------------------------------------------
extern "C" void kernel_launch(void* const* d_in, const int* in_sizes, int n_in,
                              void* d_out, int out_size, void* d_ws, size_t ws_size,
                              hipStream_t stream)
{
  (void)in_sizes; (void)n_in; (void)out_size;
  const int*   toks = (const int*)  d_in[0];
  const float* temb = (const float*)d_in[1];
  const float* pemb = (const float*)d_in[2];
  const float* Wq  = (const float*)d_in[3];  const float* bq  = (const float*)d_in[4];
  const float* Wk  = (const float*)d_in[5];  const float* bk  = (const float*)d_in[6];
  const float* Wv  = (const float*)d_in[7];  const float* bv  = (const float*)d_in[8];
  const float* Wo  = (const float*)d_in[9];  const float* bo  = (const float*)d_in[10];
  const float* g1  = (const float*)d_in[11]; const float* be1 = (const float*)d_in[12];
  const float* W1  = (const float*)d_in[13]; const float* bf1 = (const float*)d_in[14];
  const float* W2  = (const float*)d_in[15]; const float* bf2 = (const float*)d_in[16];
  const float* g2  = (const float*)d_in[17]; const float* be2 = (const float*)d_in[18];
  const float* gf  = (const float*)d_in[19]; const float* bfb = (const float*)d_in[20];

  char* p = (char*)d_ws;
  auto carve = [&](size_t bytes) -> char* {
    char* r = p;
    p += (bytes + 255) & ~(size_t)255;
    return r;
  };
  short* h     = (short*)carve((size_t)TOKENS * DM * 2);
  char*  uni   = p;
  short* tembb = (short*)uni;  // bf16 tok_emb overlaps dead weight region at the end
  short* Wqkvt = (short*)carve((size_t)NLAYER * 3072 * DM * 2);
  short* Wot   = (short*)carve((size_t)NLAYER * DM * DM * 2);
  short* W1t   = (short*)carve((size_t)NLAYER * DM * DFFN * 2);
  short* W2t   = (short*)carve((size_t)NLAYER * DM * DFFN * 2);
  float* x     = (float*)carve((size_t)TOKENS * DM * 4);
  short* qkv   = (short*)carve((size_t)TOKENS * 3072 * 2);
  short* attn  = (short*)carve((size_t)TOKENS * DM * 2);   // distinct: flash reads qkv
  short* Vt    = (short*)carve((size_t)NBATCH * NHEAD * DH * SEQL * 2);
  short* ffb   = (short*)carve((size_t)TOKENS * DFFN * 2);
  float* bqkv  = (float*)carve((size_t)NLAYER * 3072 * 4);
  size_t used = (size_t)(p - (char*)d_ws);
  size_t need_t = (size_t)(uni - (char*)d_ws) + (size_t)NVOCAB * DM * 2;
  if (used > ws_size || need_t > ws_size) return;

  dim3 tb(32, 8);

  embed_k<<<TOKENS, 256, 0, stream>>>(toks, temb, pemb, x);
  bias_cat<<<dim3(12, NLAYER), 256, 0, stream>>>(bq, bk, bv, bqkv);
  wtrans<<<dim3(DM / 32, DM / 32, NLAYER), tb, 0, stream>>>(Wq, Wqkvt, DM, DM, 3072L * DM);
  wtrans<<<dim3(DM / 32, DM / 32, NLAYER), tb, 0, stream>>>(Wk, Wqkvt + (size_t)DM * DM, DM, DM, 3072L * DM);
  wtrans<<<dim3(DM / 32, DM / 32, NLAYER), tb, 0, stream>>>(Wv, Wqkvt + (size_t)2 * DM * DM, DM, DM, 3072L * DM);
  wtrans<<<dim3(DM / 32, DM / 32, NLAYER), tb, 0, stream>>>(Wo, Wot, DM, DM, (long)DM * DM);
  wtrans<<<dim3(DFFN / 32, DM / 32, NLAYER), tb, 0, stream>>>(W1, W1t, DM, DFFN, (long)DM * DFFN);
  wtrans<<<dim3(DM / 32, DFFN / 32, NLAYER), tb, 0, stream>>>(W2, W2t, DFFN, DM, (long)DM * DFFN);

  for (int l = 0; l < NLAYER; ++l) {
    const size_t wqkv = (size_t)l * 3072 * DM;
    const size_t wdd  = (size_t)l * DM * DM;
    const size_t wdf  = (size_t)l * DM * DFFN;
    ln_bf16<<<TOKENS, 256, 0, stream>>>(x, g1 + l * DM, be1 + l * DM, h);
    launch_gemm<128, 128, 2, 2>(stream, h, Wqkvt + wqkv, qkv, bqkv + (size_t)l * 3072,
        nullptr, TOKENS, 3072, DM, DM, DM, 3072, 1.f, FLAG_OUTBF16);
    vtrans<<<dim3(SEQL / 32, DH / 32, NBATCH * NHEAD), tb, 0, stream>>>(qkv, Vt);
    flash_attn<<<dim3(SEQL / 64, NBATCH * NHEAD), 256, 0, stream>>>(qkv, Vt, attn);
    launch_gemm<64, 128, 1, 4>(stream, attn, Wot + wdd, x, bo + l * DM, x,
        TOKENS, DM, DM, DM, DM, DM, 1.f, 0);
    ln_bf16<<<TOKENS, 256, 0, stream>>>(x, g2 + l * DM, be2 + l * DM, h);
    launch_gemm<128, 128, 2, 2>(stream, h, W1t + wdf, ffb, bf1 + l * DFFN, nullptr,
        TOKENS, DFFN, DM, DM, DM, DFFN, 1.f, FLAG_OUTBF16 | FLAG_RELU);
    launch_gemm<64, 128, 1, 4>(stream, ffb, W2t + wdf, x, bf2 + l * DM, x,
        TOKENS, DM, DFFN, DFFN, DFFN, DM, 1.f, 0);
  }
  ln_bf16<<<TOKENS, 256, 0, stream>>>(x, gf, bfb, h);
  conv_bf16<<<(NVOCAB * DM) / (256 * 8), 256, 0, stream>>>(temb, tembb);
  launch_gemm<128, 128, 2, 2>(stream, h, tembb, d_out, nullptr, nullptr,
      TOKENS, NVOCAB, DM, DM, DM, NVOCAB, 1.f, 0);
}